// Round 5
// baseline (586.618 us; speedup 1.0000x reference)
//
#include <hip/hip_runtime.h>
#include <hip/hip_bf16.h>
#include <stdint.h>

// Neural-ODE via Kutta RK3 (h=1), bf16 MFMA GEMMs. State y fp32, operands
// bf16, accum fp32. RK3 numerics identical to R6 (absmax 0.05078, passing).
// R11: R10's gemm256 (70us, MfmaUtil 38%) spilled ~50 dwords/thread
// (WRITE_SIZE 33->60MB): acc[8][4]=128 caps arch VGPRs at 128 and the
// Z-order schedule held a(32)+b0(16)+b1(16) live all tile. Fix: b0 is
// RE-READ from LDS at p3 (4 ds_reads) so b0/b1 live ranges are disjoint
// (share regs; max live frags 48). Requires B0's LDS region to survive to
// p3 -> staging stagger: tile t+2's B0 staged during tile t+1's p0 (into
// parity P^1); A0/B1/A1 of t+2 during t's p1/p2/p3. Counted wait becomes
// vmcnt(6)/tile (in-order retirement => t+1 fully landed, t+2's 6 in
// flight). Region safety re-derived per phase. gemm8p (L3) unchanged.

#define BM 128
#define BN 256
#define BK 64

typedef __attribute__((ext_vector_type(4))) float floatx4;
typedef __attribute__((ext_vector_type(8))) short short8x;

__device__ __forceinline__ short f2bf(float f) {
  unsigned u = __builtin_bit_cast(unsigned, f);
  unsigned r = (u + 0x7fffu + ((u >> 16) & 1u)) >> 16;  // RNE
  return (short)r;
}

#define GLD16(gp, lp)                                                          \
  __builtin_amdgcn_global_load_lds(                                            \
      (const __attribute__((address_space(1))) void*)(gp),                     \
      (__attribute__((address_space(3))) void*)(lp), 16, 0, 0)

#define BAR() __builtin_amdgcn_s_barrier()
#define SP1() __builtin_amdgcn_s_setprio(1)
#define SP0() __builtin_amdgcn_s_setprio(0)
// rule 18: asm ds_read + lgkmcnt(0) must be followed by sched_barrier(0)
#define LG0()                                                                  \
  do {                                                                         \
    asm volatile("s_waitcnt lgkmcnt(0)");                                      \
    __builtin_amdgcn_sched_barrier(0);                                         \
  } while (0)
#define VMC(n) asm volatile("s_waitcnt vmcnt(" #n ")")
#define VMCM(n) asm volatile("s_waitcnt vmcnt(" #n ")" ::: "memory")

// asm ds_read_b128: compiler cannot see LDS aliasing -> no auto vmcnt(0)
#define DSR(d, b, off)                                                         \
  asm volatile("ds_read_b128 %0, %1 offset:%c2"                                \
               : "=v"(d)                                                       \
               : "v"(b), "i"(off))

// ============================================================================
// gemm256: 256x256 tile, relu+bf16 epilogue only (layers 1 and 2).
// ============================================================================
template <int K>
__global__ __launch_bounds__(512, 2) void gemm256(
    const short* __restrict__ A, const short* __restrict__ Bt,
    const float* __restrict__ bias, short* __restrict__ Cb, int N) {
  // LDS: A 2x32KB, B 2x32KB = 128KB. Parity strides 16384 shorts (32KB).
  __shared__ __align__(16) short As[2][256 * 64];
  __shared__ __align__(16) short Bs[2][256 * 64];

  const int tid = threadIdx.x;
  const int lane = tid & 63;
  const int quad = lane >> 4;
  const int l15 = lane & 15;
  const int l7 = lane & 7;
  const int wid = tid >> 6;
  const int wm = (wid >> 2) * 128;  // 2 M wave-halves of 128 rows
  const int wn = (wid & 3) * 64;    // 4 N wave-cols; per-wave out 128x64

  // XCD-aware chunked block swizzle (nwg = 256, %8==0)
  const int gx = gridDim.x;
  const int nwg = gx * gridDim.y;
  const int bid = blockIdx.y * gx + blockIdx.x;
  const int sb = (bid & 7) * (nwg >> 3) + (bid >> 3);
  const int tile_m = (sb / gx) * 256;
  const int tile_n = (sb % gx) * 256;

  // ---- staging: XOR-swizzled global source, linear LDS dest ----
  const int t8 = tid >> 3;  // [0,64)
  const int gsg = (tid & 7) ^ (t8 & 7);
  const int qpart = (t8 >> 5) * 64 + (t8 & 31);  // B row group
  const short* Ag = A + (size_t)(tile_m + t8) * K + gsg * 8;
  const short* Bg = Bt + (size_t)(tile_n + qpart) * K + gsg * 8;
  short* Al0 = &As[0][tid * 8];
  short* Bl0 = &Bs[0][qpart * 64 + (tid & 7) * 8];

  // A half h = global rows {h*64..+63} u {128+h*64..}: 2 issues of 64 rows.
#define STG_A6(P, h, ko)                                                       \
  do {                                                                         \
    GLD16(Ag + (size_t)((h) * 64) * K + (ko),                                  \
          Al0 + (P) * 16384 + (h) * 4096);                                     \
    GLD16(Ag + (size_t)(128 + (h) * 64) * K + (ko),                            \
          Al0 + (P) * 16384 + 8192 + (h) * 4096);                              \
  } while (0)
  // B half h = rows {q*64 + h*32 .. +31}, q=0..3: 2 issues.
#define STG_B6(P, h, ko)                                                       \
  do {                                                                         \
    GLD16(Bg + (size_t)((h) * 32) * K + (ko),                                  \
          Bl0 + (P) * 16384 + (h) * 2048);                                     \
    GLD16(Bg + (size_t)((h) * 32 + 128) * K + (ko),                            \
          Bl0 + (P) * 16384 + (h) * 2048 + 8192);                              \
  } while (0)

  // ---- fragment read bases (byte, undo XOR swizzle) ----
  const uint32_t asb = (uint32_t)(uintptr_t)&As[0][0];
  const uint32_t bsb = (uint32_t)(uintptr_t)&Bs[0][0];
  const uint32_t aab0 = asb + 2u * ((wm + l15) * 64 + (quad ^ l7) * 8);
  const uint32_t aab1 = asb + 2u * ((wm + l15) * 64 + (((4 + quad) ^ l7)) * 8);
  const uint32_t bab0 = bsb + 2u * ((wn + l15) * 64 + (quad ^ l7) * 8);
  const uint32_t bab1 = bsb + 2u * ((wn + l15) * 64 + (((4 + quad) ^ l7)) * 8);

#define RD_A6(dst, P, mih)                                                     \
  do {                                                                         \
    DSR(dst[0][0], aab0, (P) * 32768 + (mih) * 8192);                          \
    DSR(dst[0][1], aab1, (P) * 32768 + (mih) * 8192);                          \
    DSR(dst[1][0], aab0, (P) * 32768 + (mih) * 8192 + 2048);                   \
    DSR(dst[1][1], aab1, (P) * 32768 + (mih) * 8192 + 2048);                   \
    DSR(dst[2][0], aab0, (P) * 32768 + (mih) * 8192 + 4096);                   \
    DSR(dst[2][1], aab1, (P) * 32768 + (mih) * 8192 + 4096);                   \
    DSR(dst[3][0], aab0, (P) * 32768 + (mih) * 8192 + 6144);                   \
    DSR(dst[3][1], aab1, (P) * 32768 + (mih) * 8192 + 6144);                   \
  } while (0)
#define RD_B6(dst, P, njh)                                                     \
  do {                                                                         \
    DSR(dst[0][0], bab0, (P) * 32768 + (njh) * 4096);                          \
    DSR(dst[0][1], bab1, (P) * 32768 + (njh) * 4096);                          \
    DSR(dst[1][0], bab0, (P) * 32768 + (njh) * 4096 + 2048);                   \
    DSR(dst[1][1], bab1, (P) * 32768 + (njh) * 4096 + 2048);                   \
  } while (0)

  floatx4 acc[8][4];
#pragma unroll
  for (int i = 0; i < 8; ++i)
#pragma unroll
    for (int j = 0; j < 4; ++j) acc[i][j] = (floatx4){0.f, 0.f, 0.f, 0.f};

  // b0 is re-read from LDS at p3 => b0/b1 live ranges disjoint (share regs).
  short8x a[4][2], b0[2][2], b1[2][2];

#define MMQ6(af, bf, mi0, nj0)                                                 \
  do {                                                                         \
    _Pragma("unroll") for (int i = 0; i < 4; ++i) {                            \
      _Pragma("unroll") for (int j = 0; j < 2; ++j) {                          \
        acc[(mi0) + i][(nj0) + j] = __builtin_amdgcn_mfma_f32_16x16x32_bf16(   \
            af[i][0], bf[j][0], acc[(mi0) + i][(nj0) + j], 0, 0, 0);           \
        acc[(mi0) + i][(nj0) + j] = __builtin_amdgcn_mfma_f32_16x16x32_bf16(   \
            af[i][1], bf[j][1], acc[(mi0) + i][(nj0) + j], 0, 0, 0);           \
      }                                                                        \
    }                                                                          \
  } while (0)

  constexpr int NK = K / BK;
  int ko;

  // prologue: tile0 fully (8 loads); tile1 A0,B1,A1 (6 loads).
  // tile1's B0 is staged at tile0's p0 (stagger).
  STG_A6(0, 0, 0);
  STG_B6(0, 0, 0);
  STG_B6(0, 1, 0);
  STG_A6(0, 1, 0);
  STG_A6(1, 0, 64);
  STG_B6(1, 1, 64);
  STG_A6(1, 1, 64);
  VMC(6);  // tile0's 8 retired; tile1's 6 in flight
  BAR();
  ko = 128;  // k-offset (shorts) of tile t+2 during tile t

  // Steady tile t, parity P. Staging: p0 -> B0 of t+1 (parity P^1, ko-64);
  // p1/p2/p3 -> A0/B1/A1 of t+2 (parity P, ko). p3 re-reads b0 from LDS
  // (region B0@P only overwritten at t+1's p0, after this tile's trailing
  // barrier). vmcnt(6) at p3: issue order [..., t+1:B0, t+2:A0,B1,A1] =>
  // drains t+1 completely, leaves t+2's 6 in flight.
#define T256_STEADY(P)                                                         \
  do {                                                                         \
    RD_A6(a, P, 0);                                                            \
    RD_B6(b0, P, 0);                                                           \
    STG_B6((P) ^ 1, 0, ko - 64);                                               \
    BAR();                                                                     \
    LG0();                                                                     \
    SP1();                                                                     \
    MMQ6(a, b0, 0, 0);                                                         \
    SP0();                                                                     \
    BAR();                                                                     \
    RD_B6(b1, P, 1);                                                           \
    STG_A6(P, 0, ko);                                                          \
    BAR();                                                                     \
    LG0();                                                                     \
    SP1();                                                                     \
    MMQ6(a, b1, 0, 2);                                                         \
    SP0();                                                                     \
    BAR();                                                                     \
    RD_A6(a, P, 1);                                                            \
    STG_B6(P, 1, ko);                                                          \
    BAR();                                                                     \
    LG0();                                                                     \
    SP1();                                                                     \
    MMQ6(a, b1, 4, 2);                                                         \
    SP0();                                                                     \
    BAR();                                                                     \
    RD_B6(b0, P, 0);                                                           \
    STG_A6(P, 1, ko);                                                          \
    BAR();                                                                     \
    LG0();                                                                     \
    SP1();                                                                     \
    MMQ6(a, b0, 4, 0);                                                         \
    SP0();                                                                     \
    VMC(6);                                                                    \
    BAR();                                                                     \
    ko += 64;                                                                  \
  } while (0)

  // tile NK-2 (parity 0): stage only B0 of NK-1 at p0 (offset K-64 = ko-64);
  // vmcnt(0) at p3 drains it.
#define T256_TAIL1()                                                           \
  do {                                                                         \
    RD_A6(a, 0, 0);                                                            \
    RD_B6(b0, 0, 0);                                                           \
    STG_B6(1, 0, ko - 64);                                                     \
    BAR();                                                                     \
    LG0();                                                                     \
    SP1();                                                                     \
    MMQ6(a, b0, 0, 0);                                                         \
    SP0();                                                                     \
    BAR();                                                                     \
    RD_B6(b1, 0, 1);                                                           \
    BAR();                                                                     \
    LG0();                                                                     \
    SP1();                                                                     \
    MMQ6(a, b1, 0, 2);                                                         \
    SP0();                                                                     \
    BAR();                                                                     \
    RD_A6(a, 0, 1);                                                            \
    BAR();                                                                     \
    LG0();                                                                     \
    SP1();                                                                     \
    MMQ6(a, b1, 4, 2);                                                         \
    SP0();                                                                     \
    BAR();                                                                     \
    RD_B6(b0, 0, 0);                                                           \
    BAR();                                                                     \
    LG0();                                                                     \
    SP1();                                                                     \
    MMQ6(a, b0, 4, 0);                                                         \
    SP0();                                                                     \
    VMCM(0);                                                                   \
    BAR();                                                                     \
  } while (0)

  // tile NK-1 (parity 1): last tile; re-read b0 at p3 (region untouched).
#define T256_TAIL2()                                                           \
  do {                                                                         \
    RD_A6(a, 1, 0);                                                            \
    RD_B6(b0, 1, 0);                                                           \
    LG0();                                                                     \
    SP1();                                                                     \
    MMQ6(a, b0, 0, 0);                                                         \
    SP0();                                                                     \
    RD_B6(b1, 1, 1);                                                           \
    LG0();                                                                     \
    SP1();                                                                     \
    MMQ6(a, b1, 0, 2);                                                         \
    SP0();                                                                     \
    RD_A6(a, 1, 1);                                                            \
    LG0();                                                                     \
    SP1();                                                                     \
    MMQ6(a, b1, 4, 2);                                                         \
    SP0();                                                                     \
    RD_B6(b0, 1, 0);                                                           \
    LG0();                                                                     \
    SP1();                                                                     \
    MMQ6(a, b0, 4, 0);                                                         \
    SP0();                                                                     \
  } while (0)

  for (int it = 0; it < (NK - 2) / 2; ++it) {
    T256_STEADY(0);
    T256_STEADY(1);
  }
  T256_TAIL1();
  T256_TAIL2();

  // epilogue (mode-0 only): Cb = bf16(relu(v + bias))
#pragma unroll
  for (int n = 0; n < 4; ++n) {
    const int col = tile_n + wn + n * 16 + l15;
    const float bv = bias[col];
#pragma unroll
    for (int m = 0; m < 8; ++m) {
      const int row0 = tile_m + wm + m * 16 + quad * 4;
#pragma unroll
      for (int r = 0; r < 4; ++r) {
        const size_t idx = (size_t)(row0 + r) * N + col;
        float v = acc[m][n][r] + bv;
        v = v > 0.f ? v : 0.f;
        Cb[idx] = f2bf(v);
      }
    }
  }
}

// ============================================================================
// gemm8p: 128x256 tile (R9, proven, no spill). Used for layer 3 (N=1024).
// ============================================================================
template <int K, int MODE>
__global__ __launch_bounds__(512, 2) void gemm8p(
    const short* __restrict__ A, const short* __restrict__ Bt,
    const float* __restrict__ bias, short* __restrict__ Cb,
    float* __restrict__ accbuf, const float* __restrict__ y,
    float* __restrict__ yout, short* __restrict__ ytbf, int N) {
  __shared__ __align__(16) short As[2][BM * BK];
  __shared__ __align__(16) short Bs[2][BN * BK];

  const int tid = threadIdx.x;
  const int lane = tid & 63;
  const int quad = lane >> 4;
  const int l15 = lane & 15;
  const int l7 = lane & 7;
  const int wid = tid >> 6;
  const int wm = (wid >> 2) * 64;
  const int wn = (wid & 3) * 64;

  const int gx = gridDim.x;
  const int nwg = gx * gridDim.y;
  const int bid = blockIdx.y * gx + blockIdx.x;
  const int sb = (bid & 7) * (nwg >> 3) + (bid >> 3);
  const int tile_m = (sb / gx) * BM;
  const int tile_n = (sb % gx) * BN;

  const int t8 = tid >> 3;
  const int gsg = (tid & 7) ^ (t8 & 7);
  const int qpart = (t8 >> 5) * 64 + (t8 & 31);
  const short* Ag = A + (size_t)(tile_m + t8) * K + gsg * 8;
  const short* Bg = Bt + (size_t)(tile_n + qpart) * K + gsg * 8;
  short* Al0 = &As[0][tid * 8];
  short* Bl0 = &Bs[0][qpart * 64 + (tid & 7) * 8];

#define STG_A(P, ko)                                                           \
  do {                                                                         \
    GLD16(Ag + (ko), Al0 + (P) * 8192);                                        \
    GLD16(Ag + (size_t)64 * K + (ko), Al0 + (P) * 8192 + 4096);                \
  } while (0)
#define STG_B(P, h, ko)                                                        \
  do {                                                                         \
    GLD16(Bg + (size_t)((h) * 32) * K + (ko),                                  \
          Bl0 + (P) * 16384 + (h) * 2048);                                     \
    GLD16(Bg + (size_t)((h) * 32 + 128) * K + (ko),                            \
          Bl0 + (P) * 16384 + (h) * 2048 + 8192);                              \
  } while (0)

  const uint32_t asb = (uint32_t)(uintptr_t)&As[0][0];
  const uint32_t bsb = (uint32_t)(uintptr_t)&Bs[0][0];
  const uint32_t aab0 = asb + 2u * ((wm + l15) * 64 + (quad ^ l7) * 8);
  const uint32_t aab1 = asb + 2u * ((wm + l15) * 64 + (((4 + quad) ^ l7)) * 8);
  const uint32_t bab0 = bsb + 2u * ((wn + l15) * 64 + (quad ^ l7) * 8);
  const uint32_t bab1 = bsb + 2u * ((wn + l15) * 64 + (((4 + quad) ^ l7)) * 8);

#define RD_A(dst, P, mih)                                                      \
  do {                                                                         \
    DSR(dst[0][0], aab0, (P) * 16384 + (mih) * 4096);                          \
    DSR(dst[0][1], aab1, (P) * 16384 + (mih) * 4096);                          \
    DSR(dst[1][0], aab0, (P) * 16384 + (mih) * 4096 + 2048);                   \
    DSR(dst[1][1], aab1, (P) * 16384 + (mih) * 4096 + 2048);                   \
  } while (0)
#define RD_B(dst, P, njh)                                                      \
  do {                                                                         \
    DSR(dst[0][0], bab0, (P) * 32768 + (njh) * 4096);                          \
    DSR(dst[0][1], bab1, (P) * 32768 + (njh) * 4096);                          \
    DSR(dst[1][0], bab0, (P) * 32768 + (njh) * 4096 + 2048);                   \
    DSR(dst[1][1], bab1, (P) * 32768 + (njh) * 4096 + 2048);                   \
  } while (0)

  floatx4 acc[4][4];
#pragma unroll
  for (int i = 0; i < 4; ++i)
#pragma unroll
    for (int j = 0; j < 4; ++j) acc[i][j] = (floatx4){0.f, 0.f, 0.f, 0.f};

  short8x a[2][2], b0[2][2], b1[2][2];

#define MMQ(af, bf, mi0, nj0)                                                  \
  do {                                                                         \
    _Pragma("unroll") for (int i = 0; i < 2; ++i) {                            \
      _Pragma("unroll") for (int j = 0; j < 2; ++j) {                          \
        acc[(mi0) + i][(nj0) + j] = __builtin_amdgcn_mfma_f32_16x16x32_bf16(   \
            af[i][0], bf[j][0], acc[(mi0) + i][(nj0) + j], 0, 0, 0);           \
        acc[(mi0) + i][(nj0) + j] = __builtin_amdgcn_mfma_f32_16x16x32_bf16(   \
            af[i][1], bf[j][1], acc[(mi0) + i][(nj0) + j], 0, 0, 0);           \
      }                                                                        \
    }                                                                          \
  } while (0)

  constexpr int NK = K / BK;
  int ko;

  STG_B(0, 0, 0);
  STG_B(0, 1, 0);
  STG_A(0, 0);
  STG_B(1, 0, 64);
  STG_B(1, 1, 64);
  STG_A(1, 64);
  VMC(6);
  BAR();
  ko = 128;

#define TILE_STEADY(P)                                                         \
  do {                                                                         \
    RD_A(a, P, 0);                                                             \
    RD_B(b0, P, 0);                                                            \
    BAR();                                                                     \
    LG0();                                                                     \
    SP1();                                                                     \
    MMQ(a, b0, 0, 0);                                                          \
    SP0();                                                                     \
    BAR();                                                                     \
    RD_B(b1, P, 1);                                                            \
    STG_B(P, 0, ko);                                                           \
    BAR();                                                                     \
    LG0();                                                                     \
    SP1();                                                                     \
    MMQ(a, b1, 0, 2);                                                          \
    SP0();                                                                     \
    BAR();                                                                     \
    RD_A(a, P, 1);                                                             \
    STG_B(P, 1, ko);                                                           \
    BAR();                                                                     \
    LG0();                                                                     \
    SP1();                                                                     \
    MMQ(a, b1, 2, 2);                                                          \
    SP0();                                                                     \
    BAR();                                                                     \
    STG_A(P, ko);                                                              \
    BAR();                                                                     \
    SP1();                                                                     \
    MMQ(a, b0, 2, 0);                                                          \
    SP0();                                                                     \
    VMC(6);                                                                    \
    BAR();                                                                     \
    ko += 64;                                                                  \
  } while (0)

#define TILE_TAIL1()                                                           \
  do {                                                                         \
    RD_A(a, 0, 0);                                                             \
    RD_B(b0, 0, 0);                                                            \
    BAR();                                                                     \
    LG0();                                                                     \
    SP1();                                                                     \
    MMQ(a, b0, 0, 0);                                                          \
    SP0();                                                                     \
    BAR();                                                                     \
    RD_B(b1, 0, 1);                                                            \
    BAR();                                                                     \
    LG0();                                                                     \
    SP1();                                                                     \
    MMQ(a, b1, 0, 2);                                                          \
    SP0();                                                                     \
    BAR();                                                                     \
    RD_A(a, 0, 1);                                                             \
    BAR();                                                                     \
    LG0();                                                                     \
    SP1();                                                                     \
    MMQ(a, b1, 2, 2);                                                          \
    SP0();                                                                     \
    BAR();                                                                     \
    SP1();                                                                     \
    MMQ(a, b0, 2, 0);                                                          \
    SP0();                                                                     \
    VMCM(0);                                                                   \
    BAR();                                                                     \
  } while (0)

#define TILE_TAIL2()                                                           \
  do {                                                                         \
    RD_A(a, 1, 0);                                                             \
    RD_B(b0, 1, 0);                                                            \
    RD_B(b1, 1, 1);                                                            \
    LG0();                                                                     \
    SP1();                                                                     \
    MMQ(a, b0, 0, 0);                                                          \
    MMQ(a, b1, 0, 2);                                                          \
    SP0();                                                                     \
    RD_A(a, 1, 1);                                                             \
    LG0();                                                                     \
    SP1();                                                                     \
    MMQ(a, b1, 2, 2);                                                          \
    MMQ(a, b0, 2, 0);                                                          \
    SP0();                                                                     \
  } while (0)

  for (int it = 0; it < (NK - 2) / 2; ++it) {
    TILE_STEADY(0);
    TILE_STEADY(1);
  }
  TILE_TAIL1();
  TILE_TAIL2();

#pragma unroll
  for (int n = 0; n < 4; ++n) {
    const int col = tile_n + wn + n * 16 + l15;
    const float bv = bias[col];
#pragma unroll
    for (int m = 0; m < 4; ++m) {
      const int row0 = tile_m + wm + m * 16 + quad * 4;
#pragma unroll
      for (int r = 0; r < 4; ++r) {
        const size_t idx = (size_t)(row0 + r) * N + col;
        float v = acc[m][n][r] + bv;
        if (MODE == 0) {
          v = v > 0.f ? v : 0.f;
          Cb[idx] = f2bf(v);
        } else if (MODE == 1) {
          accbuf[idx] = v;
          ytbf[idx] = f2bf(y[idx] + 0.5f * v);
        } else if (MODE == 2) {
          float a2 = accbuf[idx];
          accbuf[idx] = a2 + 4.f * v;
          ytbf[idx] = f2bf(y[idx] - a2 + 2.f * v);
        } else {
          yout[idx] = y[idx] + (1.f / 6.f) * (accbuf[idx] + v);
        }
      }
    }
  }
}

// W[K][N] fp32 -> Wt[N][K] bf16 (B^T layout)
__global__ __launch_bounds__(256) void transpose_bf16(
    const float* __restrict__ W, short* __restrict__ Wt, int K, int N) {
  __shared__ float t[32][33];
  int tx = threadIdx.x & 31, ty = threadIdx.x >> 5;
  int k0 = blockIdx.y * 32, n0 = blockIdx.x * 32;
#pragma unroll
  for (int r = 0; r < 32; r += 8)
    t[ty + r][tx] = W[(size_t)(k0 + ty + r) * N + (n0 + tx)];
  __syncthreads();
#pragma unroll
  for (int r = 0; r < 32; r += 8)
    Wt[(size_t)(n0 + ty + r) * K + (k0 + tx)] = f2bf(t[tx][ty + r]);
}

__global__ __launch_bounds__(256) void init_y_kernel(
    const float* __restrict__ x, float* __restrict__ y,
    short* __restrict__ ybf, int n4) {
  int i = blockIdx.x * 256 + threadIdx.x;
  if (i >= n4) return;
  float4 v = ((const float4*)x)[i];
  ((float4*)y)[i] = v;
  short4 b;
  b.x = f2bf(v.x);
  b.y = f2bf(v.y);
  b.z = f2bf(v.z);
  b.w = f2bf(v.w);
  ((short4*)ybf)[i] = b;
}

extern "C" void kernel_launch(void* const* d_in, const int* in_sizes, int n_in,
                              void* d_out, int out_size, void* d_ws,
                              size_t ws_size, hipStream_t stream) {
  const float* x = (const float*)d_in[0];
  const float* W1 = (const float*)d_in[1];
  const float* b1 = (const float*)d_in[2];
  const float* W2 = (const float*)d_in[3];
  const float* b2 = (const float*)d_in[4];
  const float* W3 = (const float*)d_in[5];
  const float* b3 = (const float*)d_in[6];

  const int B = 8192, D = 1024, H = 2048;
  char* ws = (char*)d_ws;
  short* W1t = (short*)(ws + (0ull << 20));   // [H,D] bf16   4 MB
  short* W2t = (short*)(ws + (4ull << 20));   // [H,H] bf16   8 MB
  short* W3t = (short*)(ws + (12ull << 20));  // [D,H] bf16   4 MB
  short* ybf = (short*)(ws + (16ull << 20));  // [B,D] bf16  16 MB
  short* h1 = (short*)(ws + (32ull << 20));   // [B,H] bf16  32 MB
  short* h2 = (short*)(ws + (64ull << 20));   // [B,H] bf16  32 MB
  float* acc = (float*)(ws + (96ull << 20));  // [B,D] f32   32 MB
  float* y = (float*)(ws + (128ull << 20));   // [B,D] f32   32 MB
  float* out = (float*)d_out;

  transpose_bf16<<<dim3(H / 32, D / 32), 256, 0, stream>>>(W1, W1t, D, H);
  transpose_bf16<<<dim3(H / 32, H / 32), 256, 0, stream>>>(W2, W2t, H, H);
  transpose_bf16<<<dim3(D / 32, H / 32), 256, 0, stream>>>(W3, W3t, H, D);
  init_y_kernel<<<(B * D / 4 + 255) / 256, 256, 0, stream>>>(x, y, ybf,
                                                             B * D / 4);

  const dim3 g12(H / 256, B / 256);  // (8, 32) = 256 blocks, 1/CU
  const dim3 g3(D / BN, B / BM);     // (4, 64) = 256 blocks

  // Kutta RK3, single step h=1: stages mode 1, 2, 3.
  for (int stg = 1; stg <= 3; ++stg) {
    gemm256<1024><<<g12, 512, 0, stream>>>(ybf, W1t, b1, h1, H);
    gemm256<2048><<<g12, 512, 0, stream>>>(h1, W2t, b2, h2, H);
    if (stg == 1)
      gemm8p<2048, 1><<<g3, 512, 0, stream>>>(h2, W3t, b3, nullptr, acc, y,
                                              nullptr, ybf, D);
    else if (stg == 2)
      gemm8p<2048, 2><<<g3, 512, 0, stream>>>(h2, W3t, b3, nullptr, acc, y,
                                              nullptr, ybf, D);
    else
      gemm8p<2048, 3><<<g3, 512, 0, stream>>>(h2, W3t, b3, nullptr, acc, y,
                                              out, ybf, D);
  }
}

// Round 6
// 565.351 us; speedup vs baseline: 1.0376x; 1.0376x over previous
//
#include <hip/hip_runtime.h>
#include <hip/hip_bf16.h>
#include <stdint.h>

// Neural-ODE via Kutta RK3 (h=1), bf16 MFMA GEMMs. State y fp32, operands
// bf16, accum fp32. RK3 numerics identical to R6 (absmax 0.05078, passing).
// R12: base = R10 (563us, best; R11's b0-reread regressed and is reverted).
// Change: counted lgkmcnt pipelining of fragment reads into the MFMA
// clusters. R10 did reads -> BAR -> lgkmcnt(0) -> 16 MFMA, exposing the
// full ds_read latency (~150-250cy) after every barrier. Now: B-frags
// issued before A-frags, and the cluster runs
//   lgkmcnt(6); 4 MFMA; lgkmcnt(4); 4 MFMA; lgkmcnt(2); 4; lgkmcnt(0); 4
// (each wait + sched_barrier(0), rule 18) so the read tail drains under
// MFMA issue. ds_reads retire in-order per wave => counts exact; GLD16 is
// vmcnt not lgkm => staging doesn't perturb counts. Staging schedule,
// counted vmcnt, barriers: identical to R10.

#define BM 128
#define BN 256
#define BK 64

typedef __attribute__((ext_vector_type(4))) float floatx4;
typedef __attribute__((ext_vector_type(8))) short short8x;

__device__ __forceinline__ short f2bf(float f) {
  unsigned u = __builtin_bit_cast(unsigned, f);
  unsigned r = (u + 0x7fffu + ((u >> 16) & 1u)) >> 16;  // RNE
  return (short)r;
}

#define GLD16(gp, lp)                                                          \
  __builtin_amdgcn_global_load_lds(                                            \
      (const __attribute__((address_space(1))) void*)(gp),                     \
      (__attribute__((address_space(3))) void*)(lp), 16, 0, 0)

#define BAR() __builtin_amdgcn_s_barrier()
#define SP1() __builtin_amdgcn_s_setprio(1)
#define SP0() __builtin_amdgcn_s_setprio(0)
// rule 18: asm ds_read + lgkm wait must be followed by sched_barrier(0)
#define LG0()                                                                  \
  do {                                                                         \
    asm volatile("s_waitcnt lgkmcnt(0)");                                      \
    __builtin_amdgcn_sched_barrier(0);                                         \
  } while (0)
#define LGC(n)                                                                 \
  do {                                                                         \
    asm volatile("s_waitcnt lgkmcnt(" #n ")");                                 \
    __builtin_amdgcn_sched_barrier(0);                                         \
  } while (0)
#define VMC(n) asm volatile("s_waitcnt vmcnt(" #n ")")
#define VMCM(n) asm volatile("s_waitcnt vmcnt(" #n ")" ::: "memory")

// asm ds_read_b128: compiler cannot see LDS aliasing -> no auto vmcnt(0)
#define DSR(d, b, off)                                                         \
  asm volatile("ds_read_b128 %0, %1 offset:%c2"                                \
               : "=v"(d)                                                       \
               : "v"(b), "i"(off))

// one (i,j) accumulator position, both K-halves: 2 MFMA
#define MM2(af, bf, I, J, MI, NJ)                                              \
  do {                                                                         \
    acc[(MI) + (I)][(NJ) + (J)] = __builtin_amdgcn_mfma_f32_16x16x32_bf16(     \
        af[I][0], bf[J][0], acc[(MI) + (I)][(NJ) + (J)], 0, 0, 0);             \
    acc[(MI) + (I)][(NJ) + (J)] = __builtin_amdgcn_mfma_f32_16x16x32_bf16(     \
        af[I][1], bf[J][1], acc[(MI) + (I)][(NJ) + (J)], 0, 0, 0);             \
  } while (0)

// ============================================================================
// gemm256: 256x256 tile, relu+bf16 epilogue only (layers 1 and 2).
// ============================================================================
template <int K>
__global__ __launch_bounds__(512, 2) void gemm256(
    const short* __restrict__ A, const short* __restrict__ Bt,
    const float* __restrict__ bias, short* __restrict__ Cb, int N) {
  // LDS: A 2x32KB, B 2x32KB = 128KB. Parity strides 16384 shorts (32KB).
  __shared__ __align__(16) short As[2][256 * 64];
  __shared__ __align__(16) short Bs[2][256 * 64];

  const int tid = threadIdx.x;
  const int lane = tid & 63;
  const int quad = lane >> 4;
  const int l15 = lane & 15;
  const int l7 = lane & 7;
  const int wid = tid >> 6;
  const int wm = (wid >> 2) * 128;  // 2 M wave-halves of 128 rows
  const int wn = (wid & 3) * 64;    // 4 N wave-cols; per-wave out 128x64

  // XCD-aware chunked block swizzle (nwg = 256, %8==0)
  const int gx = gridDim.x;
  const int nwg = gx * gridDim.y;
  const int bid = blockIdx.y * gx + blockIdx.x;
  const int sb = (bid & 7) * (nwg >> 3) + (bid >> 3);
  const int tile_m = (sb / gx) * 256;
  const int tile_n = (sb % gx) * 256;

  // ---- staging: XOR-swizzled global source, linear LDS dest ----
  const int t8 = tid >> 3;  // [0,64)
  const int gsg = (tid & 7) ^ (t8 & 7);
  const int qpart = (t8 >> 5) * 64 + (t8 & 31);  // B row group
  const short* Ag = A + (size_t)(tile_m + t8) * K + gsg * 8;
  const short* Bg = Bt + (size_t)(tile_n + qpart) * K + gsg * 8;
  short* Al0 = &As[0][tid * 8];
  short* Bl0 = &Bs[0][qpart * 64 + (tid & 7) * 8];

  // A half h = global rows {h*64..+63} u {128+h*64..}: 2 issues of 64 rows.
#define STG_A6(P, h, ko)                                                       \
  do {                                                                         \
    GLD16(Ag + (size_t)((h) * 64) * K + (ko),                                  \
          Al0 + (P) * 16384 + (h) * 4096);                                     \
    GLD16(Ag + (size_t)(128 + (h) * 64) * K + (ko),                            \
          Al0 + (P) * 16384 + 8192 + (h) * 4096);                              \
  } while (0)
  // B half h = rows {q*64 + h*32 .. +31}, q=0..3: 2 issues.
#define STG_B6(P, h, ko)                                                       \
  do {                                                                         \
    GLD16(Bg + (size_t)((h) * 32) * K + (ko),                                  \
          Bl0 + (P) * 16384 + (h) * 2048);                                     \
    GLD16(Bg + (size_t)((h) * 32 + 128) * K + (ko),                            \
          Bl0 + (P) * 16384 + (h) * 2048 + 8192);                              \
  } while (0)

  // ---- fragment read bases (byte, undo XOR swizzle) ----
  const uint32_t asb = (uint32_t)(uintptr_t)&As[0][0];
  const uint32_t bsb = (uint32_t)(uintptr_t)&Bs[0][0];
  const uint32_t aab0 = asb + 2u * ((wm + l15) * 64 + (quad ^ l7) * 8);
  const uint32_t aab1 = asb + 2u * ((wm + l15) * 64 + (((4 + quad) ^ l7)) * 8);
  const uint32_t bab0 = bsb + 2u * ((wn + l15) * 64 + (quad ^ l7) * 8);
  const uint32_t bab1 = bsb + 2u * ((wn + l15) * 64 + (((4 + quad) ^ l7)) * 8);

  // issue order inside RD_* matters for the counted lgkm waits:
  // a[0][0], a[0][1], a[1][0], ... (row-major by i)
#define RD_A6(dst, P, mih)                                                     \
  do {                                                                         \
    DSR(dst[0][0], aab0, (P) * 32768 + (mih) * 8192);                          \
    DSR(dst[0][1], aab1, (P) * 32768 + (mih) * 8192);                          \
    DSR(dst[1][0], aab0, (P) * 32768 + (mih) * 8192 + 2048);                   \
    DSR(dst[1][1], aab1, (P) * 32768 + (mih) * 8192 + 2048);                   \
    DSR(dst[2][0], aab0, (P) * 32768 + (mih) * 8192 + 4096);                   \
    DSR(dst[2][1], aab1, (P) * 32768 + (mih) * 8192 + 4096);                   \
    DSR(dst[3][0], aab0, (P) * 32768 + (mih) * 8192 + 6144);                   \
    DSR(dst[3][1], aab1, (P) * 32768 + (mih) * 8192 + 6144);                   \
  } while (0)
#define RD_B6(dst, P, njh)                                                     \
  do {                                                                         \
    DSR(dst[0][0], bab0, (P) * 32768 + (njh) * 4096);                          \
    DSR(dst[0][1], bab1, (P) * 32768 + (njh) * 4096);                          \
    DSR(dst[1][0], bab0, (P) * 32768 + (njh) * 4096 + 2048);                   \
    DSR(dst[1][1], bab1, (P) * 32768 + (njh) * 4096 + 2048);                   \
  } while (0)

  floatx4 acc[8][4];
#pragma unroll
  for (int i = 0; i < 8; ++i)
#pragma unroll
    for (int j = 0; j < 4; ++j) acc[i][j] = (floatx4){0.f, 0.f, 0.f, 0.f};

  short8x a[4][2], b0[2][2], b1[2][2];

#define MMQ6(af, bf, mi0, nj0)                                                 \
  do {                                                                         \
    _Pragma("unroll") for (int i = 0; i < 4; ++i) {                            \
      _Pragma("unroll") for (int j = 0; j < 2; ++j) {                          \
        acc[(mi0) + i][(nj0) + j] = __builtin_amdgcn_mfma_f32_16x16x32_bf16(   \
            af[i][0], bf[j][0], acc[(mi0) + i][(nj0) + j], 0, 0, 0);           \
        acc[(mi0) + i][(nj0) + j] = __builtin_amdgcn_mfma_f32_16x16x32_bf16(   \
            af[i][1], bf[j][1], acc[(mi0) + i][(nj0) + j], 0, 0, 0);           \
      }                                                                        \
    }                                                                          \
  } while (0)

  constexpr int NK = K / BK;
  int ko;

  // prologue: stage K-tiles 0 (P0) and 1 (P1), 8 loads each
  STG_A6(0, 0, 0);
  STG_B6(0, 0, 0);
  STG_B6(0, 1, 0);
  STG_A6(0, 1, 0);
  STG_A6(1, 0, 64);
  STG_B6(1, 0, 64);
  STG_B6(1, 1, 64);
  STG_A6(1, 1, 64);
  VMC(8);  // tile 0 landed; tile 1's 8 loads remain in flight
  BAR();
  ko = 128;

  // Z-order: p0 a_lo*b0, p1 a_lo*b1, p2 a_hi*b1, p3 a_hi*b0. Staging t+2
  // into same parity right after each region's last confirmed read; one
  // vmcnt(8) per tile (drains t+1, leaves t+2's 8 in flight).
  // Counted-lgkm MFMA clusters: B issued before A; waits descend as the
  // in-order ds_read queue drains.
#define T256_STEADY(P)                                                         \
  do {                                                                         \
    /* p0: Q0 = a_lo x b0. reads: b0(4) then a_lo(8) = 12 outstanding */       \
    RD_B6(b0, P, 0);                                                           \
    RD_A6(a, P, 0);                                                            \
    BAR();                                                                     \
    SP1();                                                                     \
    LGC(6);                                                                    \
    MM2(a, b0, 0, 0, 0, 0);                                                    \
    MM2(a, b0, 0, 1, 0, 0);                                                    \
    LGC(4);                                                                    \
    MM2(a, b0, 1, 0, 0, 0);                                                    \
    MM2(a, b0, 1, 1, 0, 0);                                                    \
    LGC(2);                                                                    \
    MM2(a, b0, 2, 0, 0, 0);                                                    \
    MM2(a, b0, 2, 1, 0, 0);                                                    \
    LGC(0);                                                                    \
    MM2(a, b0, 3, 0, 0, 0);                                                    \
    MM2(a, b0, 3, 1, 0, 0);                                                    \
    SP0();                                                                     \
    BAR();                                                                     \
    /* p1: Q1 = a_lo x b1 ; stage A0,B0 of t+2. reads: b1(4) */                \
    RD_B6(b1, P, 1);                                                           \
    STG_A6(P, 0, ko);                                                          \
    STG_B6(P, 0, ko);                                                          \
    BAR();                                                                     \
    SP1();                                                                     \
    LGC(2);                                                                    \
    MM2(a, b1, 0, 0, 0, 2);                                                    \
    MM2(a, b1, 1, 0, 0, 2);                                                    \
    MM2(a, b1, 2, 0, 0, 2);                                                    \
    MM2(a, b1, 3, 0, 0, 2);                                                    \
    LGC(0);                                                                    \
    MM2(a, b1, 0, 1, 0, 2);                                                    \
    MM2(a, b1, 1, 1, 0, 2);                                                    \
    MM2(a, b1, 2, 1, 0, 2);                                                    \
    MM2(a, b1, 3, 1, 0, 2);                                                    \
    SP0();                                                                     \
    BAR();                                                                     \
    /* p2: Q2 = a_hi x b1 ; stage B1. reads: a_hi(8) */                        \
    RD_A6(a, P, 1);                                                            \
    STG_B6(P, 1, ko);                                                          \
    BAR();                                                                     \
    SP1();                                                                     \
    LGC(6);                                                                    \
    MM2(a, b1, 0, 0, 4, 2);                                                    \
    MM2(a, b1, 0, 1, 4, 2);                                                    \
    LGC(4);                                                                    \
    MM2(a, b1, 1, 0, 4, 2);                                                    \
    MM2(a, b1, 1, 1, 4, 2);                                                    \
    LGC(2);                                                                    \
    MM2(a, b1, 2, 0, 4, 2);                                                    \
    MM2(a, b1, 2, 1, 4, 2);                                                    \
    LGC(0);                                                                    \
    MM2(a, b1, 3, 0, 4, 2);                                                    \
    MM2(a, b1, 3, 1, 4, 2);                                                    \
    SP0();                                                                     \
    BAR();                                                                     \
    /* p3: Q3 = a_hi x b0 (regs only) ; stage A1 ; vmcnt+barrier */            \
    STG_A6(P, 1, ko);                                                          \
    BAR();                                                                     \
    SP1();                                                                     \
    MMQ6(a, b0, 4, 0);                                                         \
    SP0();                                                                     \
    VMC(8);                                                                    \
    BAR();                                                                     \
    ko += 64;                                                                  \
  } while (0)

  // tile NK-2 (parity 0): no staging; vmcnt(0) at p3 drains the last tile.
#define T256_TAIL1()                                                           \
  do {                                                                         \
    RD_B6(b0, 0, 0);                                                           \
    RD_A6(a, 0, 0);                                                            \
    BAR();                                                                     \
    LG0();                                                                     \
    SP1();                                                                     \
    MMQ6(a, b0, 0, 0);                                                         \
    SP0();                                                                     \
    BAR();                                                                     \
    RD_B6(b1, 0, 1);                                                           \
    BAR();                                                                     \
    LG0();                                                                     \
    SP1();                                                                     \
    MMQ6(a, b1, 0, 2);                                                         \
    SP0();                                                                     \
    BAR();                                                                     \
    RD_A6(a, 0, 1);                                                            \
    BAR();                                                                     \
    LG0();                                                                     \
    SP1();                                                                     \
    MMQ6(a, b1, 4, 2);                                                         \
    SP0();                                                                     \
    BAR();                                                                     \
    SP1();                                                                     \
    MMQ6(a, b0, 4, 0);                                                         \
    SP0();                                                                     \
    VMCM(0);                                                                   \
    BAR();                                                                     \
  } while (0)

  // tile NK-1 (parity 1): last tile; register deps only.
#define T256_TAIL2()                                                           \
  do {                                                                         \
    RD_B6(b0, 1, 0);                                                           \
    RD_A6(a, 1, 0);                                                            \
    RD_B6(b1, 1, 1);                                                           \
    LG0();                                                                     \
    SP1();                                                                     \
    MMQ6(a, b0, 0, 0);                                                         \
    MMQ6(a, b1, 0, 2);                                                         \
    SP0();                                                                     \
    RD_A6(a, 1, 1);                                                            \
    LG0();                                                                     \
    SP1();                                                                     \
    MMQ6(a, b1, 4, 2);                                                         \
    MMQ6(a, b0, 4, 0);                                                         \
    SP0();                                                                     \
  } while (0)

  for (int it = 0; it < (NK - 2) / 2; ++it) {
    T256_STEADY(0);
    T256_STEADY(1);
  }
  T256_TAIL1();
  T256_TAIL2();

  // epilogue (mode-0 only): Cb = bf16(relu(v + bias))
#pragma unroll
  for (int n = 0; n < 4; ++n) {
    const int col = tile_n + wn + n * 16 + l15;
    const float bv = bias[col];
#pragma unroll
    for (int m = 0; m < 8; ++m) {
      const int row0 = tile_m + wm + m * 16 + quad * 4;
#pragma unroll
      for (int r = 0; r < 4; ++r) {
        const size_t idx = (size_t)(row0 + r) * N + col;
        float v = acc[m][n][r] + bv;
        v = v > 0.f ? v : 0.f;
        Cb[idx] = f2bf(v);
      }
    }
  }
}

// ============================================================================
// gemm8p: 128x256 tile (R9 base + counted lgkm). Used for layer 3 (N=1024).
// ============================================================================
template <int K, int MODE>
__global__ __launch_bounds__(512, 2) void gemm8p(
    const short* __restrict__ A, const short* __restrict__ Bt,
    const float* __restrict__ bias, short* __restrict__ Cb,
    float* __restrict__ accbuf, const float* __restrict__ y,
    float* __restrict__ yout, short* __restrict__ ytbf, int N) {
  __shared__ __align__(16) short As[2][BM * BK];
  __shared__ __align__(16) short Bs[2][BN * BK];

  const int tid = threadIdx.x;
  const int lane = tid & 63;
  const int quad = lane >> 4;
  const int l15 = lane & 15;
  const int l7 = lane & 7;
  const int wid = tid >> 6;
  const int wm = (wid >> 2) * 64;
  const int wn = (wid & 3) * 64;

  const int gx = gridDim.x;
  const int nwg = gx * gridDim.y;
  const int bid = blockIdx.y * gx + blockIdx.x;
  const int sb = (bid & 7) * (nwg >> 3) + (bid >> 3);
  const int tile_m = (sb / gx) * BM;
  const int tile_n = (sb % gx) * BN;

  const int t8 = tid >> 3;
  const int gsg = (tid & 7) ^ (t8 & 7);
  const int qpart = (t8 >> 5) * 64 + (t8 & 31);
  const short* Ag = A + (size_t)(tile_m + t8) * K + gsg * 8;
  const short* Bg = Bt + (size_t)(tile_n + qpart) * K + gsg * 8;
  short* Al0 = &As[0][tid * 8];
  short* Bl0 = &Bs[0][qpart * 64 + (tid & 7) * 8];

#define STG_A(P, ko)                                                           \
  do {                                                                         \
    GLD16(Ag + (ko), Al0 + (P) * 8192);                                        \
    GLD16(Ag + (size_t)64 * K + (ko), Al0 + (P) * 8192 + 4096);                \
  } while (0)
#define STG_B(P, h, ko)                                                        \
  do {                                                                         \
    GLD16(Bg + (size_t)((h) * 32) * K + (ko),                                  \
          Bl0 + (P) * 16384 + (h) * 2048);                                     \
    GLD16(Bg + (size_t)((h) * 32 + 128) * K + (ko),                            \
          Bl0 + (P) * 16384 + (h) * 2048 + 8192);                              \
  } while (0)

  const uint32_t asb = (uint32_t)(uintptr_t)&As[0][0];
  const uint32_t bsb = (uint32_t)(uintptr_t)&Bs[0][0];
  const uint32_t aab0 = asb + 2u * ((wm + l15) * 64 + (quad ^ l7) * 8);
  const uint32_t aab1 = asb + 2u * ((wm + l15) * 64 + (((4 + quad) ^ l7)) * 8);
  const uint32_t bab0 = bsb + 2u * ((wn + l15) * 64 + (quad ^ l7) * 8);
  const uint32_t bab1 = bsb + 2u * ((wn + l15) * 64 + (((4 + quad) ^ l7)) * 8);

#define RD_A(dst, P, mih)                                                      \
  do {                                                                         \
    DSR(dst[0][0], aab0, (P) * 16384 + (mih) * 4096);                          \
    DSR(dst[0][1], aab1, (P) * 16384 + (mih) * 4096);                          \
    DSR(dst[1][0], aab0, (P) * 16384 + (mih) * 4096 + 2048);                   \
    DSR(dst[1][1], aab1, (P) * 16384 + (mih) * 4096 + 2048);                   \
  } while (0)
#define RD_B(dst, P, njh)                                                      \
  do {                                                                         \
    DSR(dst[0][0], bab0, (P) * 32768 + (njh) * 4096);                          \
    DSR(dst[0][1], bab1, (P) * 32768 + (njh) * 4096);                          \
    DSR(dst[1][0], bab0, (P) * 32768 + (njh) * 4096 + 2048);                   \
    DSR(dst[1][1], bab1, (P) * 32768 + (njh) * 4096 + 2048);                   \
  } while (0)

  floatx4 acc[4][4];
#pragma unroll
  for (int i = 0; i < 4; ++i)
#pragma unroll
    for (int j = 0; j < 4; ++j) acc[i][j] = (floatx4){0.f, 0.f, 0.f, 0.f};

  short8x a[2][2], b0[2][2], b1[2][2];

#define MMQ(af, bf, mi0, nj0)                                                  \
  do {                                                                         \
    _Pragma("unroll") for (int i = 0; i < 2; ++i) {                            \
      _Pragma("unroll") for (int j = 0; j < 2; ++j) {                          \
        acc[(mi0) + i][(nj0) + j] = __builtin_amdgcn_mfma_f32_16x16x32_bf16(   \
            af[i][0], bf[j][0], acc[(mi0) + i][(nj0) + j], 0, 0, 0);           \
        acc[(mi0) + i][(nj0) + j] = __builtin_amdgcn_mfma_f32_16x16x32_bf16(   \
            af[i][1], bf[j][1], acc[(mi0) + i][(nj0) + j], 0, 0, 0);           \
      }                                                                        \
    }                                                                          \
  } while (0)

  constexpr int NK = K / BK;
  int ko;

  STG_B(0, 0, 0);
  STG_B(0, 1, 0);
  STG_A(0, 0);
  STG_B(1, 0, 64);
  STG_B(1, 1, 64);
  STG_A(1, 64);
  VMC(6);
  BAR();
  ko = 128;

#define TILE_STEADY(P)                                                         \
  do {                                                                         \
    /* p0: reads b0(4) then a_lo(4) = 8 outstanding */                         \
    RD_B(b0, P, 0);                                                            \
    RD_A(a, P, 0);                                                             \
    BAR();                                                                     \
    SP1();                                                                     \
    LGC(2);                                                                    \
    MM2(a, b0, 0, 0, 0, 0);                                                    \
    MM2(a, b0, 0, 1, 0, 0);                                                    \
    LGC(0);                                                                    \
    MM2(a, b0, 1, 0, 0, 0);                                                    \
    MM2(a, b0, 1, 1, 0, 0);                                                    \
    SP0();                                                                     \
    BAR();                                                                     \
    /* p1: reads b1(4) */                                                      \
    RD_B(b1, P, 1);                                                            \
    STG_B(P, 0, ko);                                                           \
    BAR();                                                                     \
    SP1();                                                                     \
    LGC(2);                                                                    \
    MM2(a, b1, 0, 0, 0, 2);                                                    \
    MM2(a, b1, 1, 0, 0, 2);                                                    \
    LGC(0);                                                                    \
    MM2(a, b1, 0, 1, 0, 2);                                                    \
    MM2(a, b1, 1, 1, 0, 2);                                                    \
    SP0();                                                                     \
    BAR();                                                                     \
    /* p2: reads a_hi(4) */                                                    \
    RD_A(a, P, 1);                                                             \
    STG_B(P, 1, ko);                                                           \
    BAR();                                                                     \
    SP1();                                                                     \
    LGC(2);                                                                    \
    MM2(a, b1, 0, 0, 2, 2);                                                    \
    MM2(a, b1, 0, 1, 2, 2);                                                    \
    LGC(0);                                                                    \
    MM2(a, b1, 1, 0, 2, 2);                                                    \
    MM2(a, b1, 1, 1, 2, 2);                                                    \
    SP0();                                                                     \
    BAR();                                                                     \
    /* p3: regs only */                                                        \
    STG_A(P, ko);                                                              \
    BAR();                                                                     \
    SP1();                                                                     \
    MMQ(a, b0, 2, 0);                                                          \
    SP0();                                                                     \
    VMC(6);                                                                    \
    BAR();                                                                     \
    ko += 64;                                                                  \
  } while (0)

#define TILE_TAIL1()                                                           \
  do {                                                                         \
    RD_B(b0, 0, 0);                                                            \
    RD_A(a, 0, 0);                                                             \
    BAR();                                                                     \
    LG0();                                                                     \
    SP1();                                                                     \
    MMQ(a, b0, 0, 0);                                                          \
    SP0();                                                                     \
    BAR();                                                                     \
    RD_B(b1, 0, 1);                                                            \
    BAR();                                                                     \
    LG0();                                                                     \
    SP1();                                                                     \
    MMQ(a, b1, 0, 2);                                                          \
    SP0();                                                                     \
    BAR();                                                                     \
    RD_A(a, 0, 1);                                                             \
    BAR();                                                                     \
    LG0();                                                                     \
    SP1();                                                                     \
    MMQ(a, b1, 2, 2);                                                          \
    SP0();                                                                     \
    BAR();                                                                     \
    SP1();                                                                     \
    MMQ(a, b0, 2, 0);                                                          \
    SP0();                                                                     \
    VMCM(0);                                                                   \
    BAR();                                                                     \
  } while (0)

#define TILE_TAIL2()                                                           \
  do {                                                                         \
    RD_B(b0, 1, 0);                                                            \
    RD_A(a, 1, 0);                                                             \
    RD_B(b1, 1, 1);                                                            \
    LG0();                                                                     \
    SP1();                                                                     \
    MMQ(a, b0, 0, 0);                                                          \
    MMQ(a, b1, 0, 2);                                                          \
    SP0();                                                                     \
    RD_A(a, 1, 1);                                                             \
    LG0();                                                                     \
    SP1();                                                                     \
    MMQ(a, b1, 2, 2);                                                          \
    MMQ(a, b0, 2, 0);                                                          \
    SP0();                                                                     \
  } while (0)

  for (int it = 0; it < (NK - 2) / 2; ++it) {
    TILE_STEADY(0);
    TILE_STEADY(1);
  }
  TILE_TAIL1();
  TILE_TAIL2();

#pragma unroll
  for (int n = 0; n < 4; ++n) {
    const int col = tile_n + wn + n * 16 + l15;
    const float bv = bias[col];
#pragma unroll
    for (int m = 0; m < 4; ++m) {
      const int row0 = tile_m + wm + m * 16 + quad * 4;
#pragma unroll
      for (int r = 0; r < 4; ++r) {
        const size_t idx = (size_t)(row0 + r) * N + col;
        float v = acc[m][n][r] + bv;
        if (MODE == 0) {
          v = v > 0.f ? v : 0.f;
          Cb[idx] = f2bf(v);
        } else if (MODE == 1) {
          accbuf[idx] = v;
          ytbf[idx] = f2bf(y[idx] + 0.5f * v);
        } else if (MODE == 2) {
          float a2 = accbuf[idx];
          accbuf[idx] = a2 + 4.f * v;
          ytbf[idx] = f2bf(y[idx] - a2 + 2.f * v);
        } else {
          yout[idx] = y[idx] + (1.f / 6.f) * (accbuf[idx] + v);
        }
      }
    }
  }
}

// W[K][N] fp32 -> Wt[N][K] bf16 (B^T layout)
__global__ __launch_bounds__(256) void transpose_bf16(
    const float* __restrict__ W, short* __restrict__ Wt, int K, int N) {
  __shared__ float t[32][33];
  int tx = threadIdx.x & 31, ty = threadIdx.x >> 5;
  int k0 = blockIdx.y * 32, n0 = blockIdx.x * 32;
#pragma unroll
  for (int r = 0; r < 32; r += 8)
    t[ty + r][tx] = W[(size_t)(k0 + ty + r) * N + (n0 + tx)];
  __syncthreads();
#pragma unroll
  for (int r = 0; r < 32; r += 8)
    Wt[(size_t)(n0 + ty + r) * K + (k0 + tx)] = f2bf(t[tx][ty + r]);
}

__global__ __launch_bounds__(256) void init_y_kernel(
    const float* __restrict__ x, float* __restrict__ y,
    short* __restrict__ ybf, int n4) {
  int i = blockIdx.x * 256 + threadIdx.x;
  if (i >= n4) return;
  float4 v = ((const float4*)x)[i];
  ((float4*)y)[i] = v;
  short4 b;
  b.x = f2bf(v.x);
  b.y = f2bf(v.y);
  b.z = f2bf(v.z);
  b.w = f2bf(v.w);
  ((short4*)ybf)[i] = b;
}

extern "C" void kernel_launch(void* const* d_in, const int* in_sizes, int n_in,
                              void* d_out, int out_size, void* d_ws,
                              size_t ws_size, hipStream_t stream) {
  const float* x = (const float*)d_in[0];
  const float* W1 = (const float*)d_in[1];
  const float* b1 = (const float*)d_in[2];
  const float* W2 = (const float*)d_in[3];
  const float* b2 = (const float*)d_in[4];
  const float* W3 = (const float*)d_in[5];
  const float* b3 = (const float*)d_in[6];

  const int B = 8192, D = 1024, H = 2048;
  char* ws = (char*)d_ws;
  short* W1t = (short*)(ws + (0ull << 20));   // [H,D] bf16   4 MB
  short* W2t = (short*)(ws + (4ull << 20));   // [H,H] bf16   8 MB
  short* W3t = (short*)(ws + (12ull << 20));  // [D,H] bf16   4 MB
  short* ybf = (short*)(ws + (16ull << 20));  // [B,D] bf16  16 MB
  short* h1 = (short*)(ws + (32ull << 20));   // [B,H] bf16  32 MB
  short* h2 = (short*)(ws + (64ull << 20));   // [B,H] bf16  32 MB
  float* acc = (float*)(ws + (96ull << 20));  // [B,D] f32   32 MB
  float* y = (float*)(ws + (128ull << 20));   // [B,D] f32   32 MB
  float* out = (float*)d_out;

  transpose_bf16<<<dim3(H / 32, D / 32), 256, 0, stream>>>(W1, W1t, D, H);
  transpose_bf16<<<dim3(H / 32, H / 32), 256, 0, stream>>>(W2, W2t, H, H);
  transpose_bf16<<<dim3(D / 32, H / 32), 256, 0, stream>>>(W3, W3t, H, D);
  init_y_kernel<<<(B * D / 4 + 255) / 256, 256, 0, stream>>>(x, y, ybf,
                                                             B * D / 4);

  const dim3 g12(H / 256, B / 256);  // (8, 32) = 256 blocks, 1/CU
  const dim3 g3(D / BN, B / BM);     // (4, 64) = 256 blocks

  // Kutta RK3, single step h=1: stages mode 1, 2, 3.
  for (int stg = 1; stg <= 3; ++stg) {
    gemm256<1024><<<g12, 512, 0, stream>>>(ybf, W1t, b1, h1, H);
    gemm256<2048><<<g12, 512, 0, stream>>>(h1, W2t, b2, h2, H);
    if (stg == 1)
      gemm8p<2048, 1><<<g3, 512, 0, stream>>>(h2, W3t, b3, nullptr, acc, y,
                                              nullptr, ybf, D);
    else if (stg == 2)
      gemm8p<2048, 2><<<g3, 512, 0, stream>>>(h2, W3t, b3, nullptr, acc, y,
                                              nullptr, ybf, D);
    else
      gemm8p<2048, 3><<<g3, 512, 0, stream>>>(h2, W3t, b3, nullptr, acc, y,
                                              out, ybf, D);
  }
}

// Round 8
// 544.419 us; speedup vs baseline: 1.0775x; 1.0384x over previous
//
#include <hip/hip_runtime.h>
#include <hip/hip_bf16.h>
#include <stdint.h>

// Neural-ODE via Kutta RK3 (h=1), bf16 MFMA GEMMs. State y fp32, operands
// bf16, accum fp32. RK3 numerics identical to R6 (absmax 0.05078, passing).
// R13 (resubmit; round-7 bench was a container-acquisition infra failure,
// no kernel verdict): gemm256 rebuilt as a one-phase-ahead read pipeline.
// R10/R12's structure serviced each phase's ds_reads strictly before its
// MFMAs (reads issued between trailing and leading barriers -> LDS service
// time ~1500cy/tile fully exposed; counted-lgkm R12 was neutral because the
// service itself, not the wait tail, was on the critical path). Now each
// phase issues the NEXT phase's reads and runs MFMAs on the PREVIOUS
// phase's confirmed frags: LDS service hides under the 620cy MFMA windows,
// every lgkmcnt(0) is a zero-wait confirm, and barriers drop 8->4/tile.
//  - Z-order Q0(a0b0) Q1(a0b1) Q2(a1b1) Q3(a1b0); p3 prefetches next
//    tile's a0+b0 from parity P^1 (vmcnt(6) drains exactly the prev tile's
//    staging of tile t+1, then BAR -> cross-wave DMA visibility).
//  - staging 2 GLD16/phase: A0@p0, B1@p1, A1@p2, B0@p3, each after the
//    region's last reads are LGC-confirmed + barrier'd.
//  - b-register roles alternate per tile (prefetched b0' lands in the
//    dead b1 slots); two-tile unrolled loop.
//  - frag alloc 96 VGPR + acc 128 AGPR (watch for spill).
// gemm8p (layer 3) unchanged from R12 (proven).

#define BM 128
#define BN 256
#define BK 64

typedef __attribute__((ext_vector_type(4))) float floatx4;
typedef __attribute__((ext_vector_type(8))) short short8x;

__device__ __forceinline__ short f2bf(float f) {
  unsigned u = __builtin_bit_cast(unsigned, f);
  unsigned r = (u + 0x7fffu + ((u >> 16) & 1u)) >> 16;  // RNE
  return (short)r;
}

#define GLD16(gp, lp)                                                          \
  __builtin_amdgcn_global_load_lds(                                            \
      (const __attribute__((address_space(1))) void*)(gp),                     \
      (__attribute__((address_space(3))) void*)(lp), 16, 0, 0)

#define BAR() __builtin_amdgcn_s_barrier()
#define SP1() __builtin_amdgcn_s_setprio(1)
#define SP0() __builtin_amdgcn_s_setprio(0)
#define SB() __builtin_amdgcn_sched_barrier(0)
// rule 18: asm ds_read + lgkm wait must be followed by sched_barrier(0)
#define LG0()                                                                  \
  do {                                                                         \
    asm volatile("s_waitcnt lgkmcnt(0)");                                      \
    __builtin_amdgcn_sched_barrier(0);                                         \
  } while (0)
#define LGC(n)                                                                 \
  do {                                                                         \
    asm volatile("s_waitcnt lgkmcnt(" #n ")");                                 \
    __builtin_amdgcn_sched_barrier(0);                                         \
  } while (0)
#define VMC(n) asm volatile("s_waitcnt vmcnt(" #n ")")
#define VMCM(n) asm volatile("s_waitcnt vmcnt(" #n ")" ::: "memory")

// asm ds_read_b128: compiler cannot see LDS aliasing -> no auto vmcnt(0)
#define DSR(d, b, off)                                                         \
  asm volatile("ds_read_b128 %0, %1 offset:%c2"                                \
               : "=v"(d)                                                       \
               : "v"(b), "i"(off))

// one (i,j) accumulator position, both K-halves: 2 MFMA
#define MM2(af, bf, I, J, MI, NJ)                                              \
  do {                                                                         \
    acc[(MI) + (I)][(NJ) + (J)] = __builtin_amdgcn_mfma_f32_16x16x32_bf16(     \
        af[I][0], bf[J][0], acc[(MI) + (I)][(NJ) + (J)], 0, 0, 0);             \
    acc[(MI) + (I)][(NJ) + (J)] = __builtin_amdgcn_mfma_f32_16x16x32_bf16(     \
        af[I][1], bf[J][1], acc[(MI) + (I)][(NJ) + (J)], 0, 0, 0);             \
  } while (0)

// ============================================================================
// gemm256: 256x256 tile, relu+bf16 epilogue only (layers 1 and 2).
// ============================================================================
template <int K>
__global__ __launch_bounds__(512, 2) void gemm256(
    const short* __restrict__ A, const short* __restrict__ Bt,
    const float* __restrict__ bias, short* __restrict__ Cb, int N) {
  // LDS: A 2x32KB, B 2x32KB = 128KB. Parity strides 16384 shorts (32KB).
  __shared__ __align__(16) short As[2][256 * 64];
  __shared__ __align__(16) short Bs[2][256 * 64];

  const int tid = threadIdx.x;
  const int lane = tid & 63;
  const int quad = lane >> 4;
  const int l15 = lane & 15;
  const int l7 = lane & 7;
  const int wid = tid >> 6;
  const int wm = (wid >> 2) * 128;  // 2 M wave-halves of 128 rows
  const int wn = (wid & 3) * 64;    // 4 N wave-cols; per-wave out 128x64

  // XCD-aware chunked block swizzle (nwg = 256, %8==0)
  const int gx = gridDim.x;
  const int nwg = gx * gridDim.y;
  const int bid = blockIdx.y * gx + blockIdx.x;
  const int sb = (bid & 7) * (nwg >> 3) + (bid >> 3);
  const int tile_m = (sb / gx) * 256;
  const int tile_n = (sb % gx) * 256;

  // ---- staging: XOR-swizzled global source, linear LDS dest ----
  const int t8 = tid >> 3;  // [0,64)
  const int gsg = (tid & 7) ^ (t8 & 7);
  const int qpart = (t8 >> 5) * 64 + (t8 & 31);  // B row group
  const short* Ag = A + (size_t)(tile_m + t8) * K + gsg * 8;
  const short* Bg = Bt + (size_t)(tile_n + qpart) * K + gsg * 8;
  short* Al0 = &As[0][tid * 8];
  short* Bl0 = &Bs[0][qpart * 64 + (tid & 7) * 8];

  // A half h = global rows {h*64..+63} u {128+h*64..}: 2 issues of 64 rows.
#define STG_A6(P, h, ko)                                                       \
  do {                                                                         \
    GLD16(Ag + (size_t)((h) * 64) * K + (ko),                                  \
          Al0 + (P) * 16384 + (h) * 4096);                                     \
    GLD16(Ag + (size_t)(128 + (h) * 64) * K + (ko),                            \
          Al0 + (P) * 16384 + 8192 + (h) * 4096);                              \
  } while (0)
  // B half h = rows {q*64 + h*32 .. +31}, q=0..3: 2 issues.
#define STG_B6(P, h, ko)                                                       \
  do {                                                                         \
    GLD16(Bg + (size_t)((h) * 32) * K + (ko),                                  \
          Bl0 + (P) * 16384 + (h) * 2048);                                     \
    GLD16(Bg + (size_t)((h) * 32 + 128) * K + (ko),                            \
          Bl0 + (P) * 16384 + (h) * 2048 + 8192);                              \
  } while (0)

  // ---- fragment read bases (byte, undo XOR swizzle) ----
  const uint32_t asb = (uint32_t)(uintptr_t)&As[0][0];
  const uint32_t bsb = (uint32_t)(uintptr_t)&Bs[0][0];
  const uint32_t aab0 = asb + 2u * ((wm + l15) * 64 + (quad ^ l7) * 8);
  const uint32_t aab1 = asb + 2u * ((wm + l15) * 64 + (((4 + quad) ^ l7)) * 8);
  const uint32_t bab0 = bsb + 2u * ((wn + l15) * 64 + (quad ^ l7) * 8);
  const uint32_t bab1 = bsb + 2u * ((wn + l15) * 64 + (((4 + quad) ^ l7)) * 8);

#define RD_A6(dst, P, mih)                                                     \
  do {                                                                         \
    DSR(dst[0][0], aab0, (P) * 32768 + (mih) * 8192);                          \
    DSR(dst[0][1], aab1, (P) * 32768 + (mih) * 8192);                          \
    DSR(dst[1][0], aab0, (P) * 32768 + (mih) * 8192 + 2048);                   \
    DSR(dst[1][1], aab1, (P) * 32768 + (mih) * 8192 + 2048);                   \
    DSR(dst[2][0], aab0, (P) * 32768 + (mih) * 8192 + 4096);                   \
    DSR(dst[2][1], aab1, (P) * 32768 + (mih) * 8192 + 4096);                   \
    DSR(dst[3][0], aab0, (P) * 32768 + (mih) * 8192 + 6144);                   \
    DSR(dst[3][1], aab1, (P) * 32768 + (mih) * 8192 + 6144);                   \
  } while (0)
#define RD_B6(dst, P, njh)                                                     \
  do {                                                                         \
    DSR(dst[0][0], bab0, (P) * 32768 + (njh) * 4096);                          \
    DSR(dst[0][1], bab1, (P) * 32768 + (njh) * 4096);                          \
    DSR(dst[1][0], bab0, (P) * 32768 + (njh) * 4096 + 2048);                   \
    DSR(dst[1][1], bab1, (P) * 32768 + (njh) * 4096 + 2048);                   \
  } while (0)

  floatx4 acc[8][4];
#pragma unroll
  for (int i = 0; i < 8; ++i)
#pragma unroll
    for (int j = 0; j < 4; ++j) acc[i][j] = (floatx4){0.f, 0.f, 0.f, 0.f};

  // a0: prefetched (prev tile p3), used p0/p1. a1: issued p1, used p2/p3.
  // bX/bY: b0/b1 roles alternate per tile (prefetched b0' lands in the
  // slots whose b1 died at p2).
  short8x a0[4][2], a1[4][2], bX[2][2], bY[2][2];

#define MMQ6(af, bf, mi0, nj0)                                                 \
  do {                                                                         \
    _Pragma("unroll") for (int i = 0; i < 4; ++i) {                            \
      _Pragma("unroll") for (int j = 0; j < 2; ++j) {                          \
        acc[(mi0) + i][(nj0) + j] = __builtin_amdgcn_mfma_f32_16x16x32_bf16(   \
            af[i][0], bf[j][0], acc[(mi0) + i][(nj0) + j], 0, 0, 0);           \
        acc[(mi0) + i][(nj0) + j] = __builtin_amdgcn_mfma_f32_16x16x32_bf16(   \
            af[i][1], bf[j][1], acc[(mi0) + i][(nj0) + j], 0, 0, 0);           \
      }                                                                        \
    }                                                                          \
  } while (0)

  constexpr int NK = K / BK;
  int ko;

  // prologue: stage tiles 0 (P0) and 1 (P1) fully; prefetch tile0's a0,b0.
  STG_A6(0, 0, 0);
  STG_B6(0, 0, 0);
  STG_B6(0, 1, 0);
  STG_A6(0, 1, 0);
  STG_A6(1, 0, 64);
  STG_B6(1, 0, 64);
  STG_B6(1, 1, 64);
  STG_A6(1, 1, 64);
  VMC(8);  // tile0's 8 landed; tile1's 8 in flight
  BAR();
  RD_A6(a0, 0, 0);
  RD_B6(bX, 0, 0);
  SB();
  ko = 128;

  // Steady tile t (parity P, b0 in BC, b1 in BN2):
  //  p0: confirm prefetch; BAR (A0@P free); stage A0; issue b1; Q0=a0*BC
  //  p1: confirm b1;       BAR (B1@P free); stage B1; issue a1; Q1=a0*BN2
  //  p2: confirm a1;       BAR (A1@P free); stage A1;           Q2=a1*BN2
  //  p3: vmcnt(6) (drains prev tile's staging of t+1 into P^1);
  //      BAR (t+1 data visible); stage B0; prefetch a0',b0'@P^1 (b0'->BN2);
  //      Q3=a1*BC
#define T256_STEADY(P, BC, BN2)                                                \
  do {                                                                         \
    LG0();                                                                     \
    BAR();                                                                     \
    STG_A6(P, 0, ko);                                                          \
    RD_B6(BN2, P, 1);                                                          \
    SB();                                                                      \
    SP1();                                                                     \
    MMQ6(a0, BC, 0, 0);                                                        \
    SP0();                                                                     \
    LG0();                                                                     \
    BAR();                                                                     \
    STG_B6(P, 1, ko);                                                          \
    RD_A6(a1, P, 1);                                                           \
    SB();                                                                      \
    SP1();                                                                     \
    MMQ6(a0, BN2, 0, 2);                                                       \
    SP0();                                                                     \
    LG0();                                                                     \
    BAR();                                                                     \
    STG_A6(P, 1, ko);                                                          \
    SB();                                                                      \
    SP1();                                                                     \
    MMQ6(a1, BN2, 4, 2);                                                       \
    SP0();                                                                     \
    VMC(6);                                                                    \
    BAR();                                                                     \
    STG_B6(P, 0, ko);                                                          \
    RD_A6(a0, (P) ^ 1, 0);                                                     \
    RD_B6(BN2, (P) ^ 1, 0);                                                    \
    SB();                                                                      \
    SP1();                                                                     \
    MMQ6(a1, BC, 4, 0);                                                        \
    SP0();                                                                     \
    ko += 64;                                                                  \
  } while (0)

  // tile NK-2 (P0, b0=bX): no staging; vmcnt(0) before prefetching NK-1.
#define T256_TAIL1()                                                           \
  do {                                                                         \
    LG0();                                                                     \
    BAR();                                                                     \
    RD_B6(bY, 0, 1);                                                           \
    SB();                                                                      \
    SP1();                                                                     \
    MMQ6(a0, bX, 0, 0);                                                        \
    SP0();                                                                     \
    LG0();                                                                     \
    BAR();                                                                     \
    RD_A6(a1, 0, 1);                                                           \
    SB();                                                                      \
    SP1();                                                                     \
    MMQ6(a0, bY, 0, 2);                                                        \
    SP0();                                                                     \
    LG0();                                                                     \
    BAR();                                                                     \
    SP1();                                                                     \
    MMQ6(a1, bY, 4, 2);                                                        \
    SP0();                                                                     \
    VMCM(0);                                                                   \
    BAR();                                                                     \
    RD_A6(a0, 1, 0);                                                           \
    RD_B6(bY, 1, 0);                                                           \
    SB();                                                                      \
    SP1();                                                                     \
    MMQ6(a1, bX, 4, 0);                                                        \
    SP0();                                                                     \
  } while (0)

  // tile NK-1 (P1, b0=bY): last tile, intra-wave deps only (no barriers).
#define T256_TAIL2()                                                           \
  do {                                                                         \
    LG0();                                                                     \
    RD_B6(bX, 1, 1);                                                           \
    SB();                                                                      \
    SP1();                                                                     \
    MMQ6(a0, bY, 0, 0);                                                        \
    SP0();                                                                     \
    LG0();                                                                     \
    RD_A6(a1, 1, 1);                                                           \
    SB();                                                                      \
    SP1();                                                                     \
    MMQ6(a0, bX, 0, 2);                                                        \
    SP0();                                                                     \
    LG0();                                                                     \
    SP1();                                                                     \
    MMQ6(a1, bX, 4, 2);                                                        \
    MMQ6(a1, bY, 4, 0);                                                        \
    SP0();                                                                     \
  } while (0)

  for (int it = 0; it < (NK - 2) / 2; ++it) {
    T256_STEADY(0, bX, bY);
    T256_STEADY(1, bY, bX);
  }
  T256_TAIL1();
  T256_TAIL2();

  // epilogue (mode-0 only): Cb = bf16(relu(v + bias))
#pragma unroll
  for (int n = 0; n < 4; ++n) {
    const int col = tile_n + wn + n * 16 + l15;
    const float bv = bias[col];
#pragma unroll
    for (int m = 0; m < 8; ++m) {
      const int row0 = tile_m + wm + m * 16 + quad * 4;
#pragma unroll
      for (int r = 0; r < 4; ++r) {
        const size_t idx = (size_t)(row0 + r) * N + col;
        float v = acc[m][n][r] + bv;
        v = v > 0.f ? v : 0.f;
        Cb[idx] = f2bf(v);
      }
    }
  }
}

// ============================================================================
// gemm8p: 128x256 tile (R12, proven). Used for layer 3 (N=1024).
// ============================================================================
template <int K, int MODE>
__global__ __launch_bounds__(512, 2) void gemm8p(
    const short* __restrict__ A, const short* __restrict__ Bt,
    const float* __restrict__ bias, short* __restrict__ Cb,
    float* __restrict__ accbuf, const float* __restrict__ y,
    float* __restrict__ yout, short* __restrict__ ytbf, int N) {
  __shared__ __align__(16) short As[2][BM * BK];
  __shared__ __align__(16) short Bs[2][BN * BK];

  const int tid = threadIdx.x;
  const int lane = tid & 63;
  const int quad = lane >> 4;
  const int l15 = lane & 15;
  const int l7 = lane & 7;
  const int wid = tid >> 6;
  const int wm = (wid >> 2) * 64;
  const int wn = (wid & 3) * 64;

  const int gx = gridDim.x;
  const int nwg = gx * gridDim.y;
  const int bid = blockIdx.y * gx + blockIdx.x;
  const int sb = (bid & 7) * (nwg >> 3) + (bid >> 3);
  const int tile_m = (sb / gx) * BM;
  const int tile_n = (sb % gx) * BN;

  const int t8 = tid >> 3;
  const int gsg = (tid & 7) ^ (t8 & 7);
  const int qpart = (t8 >> 5) * 64 + (t8 & 31);
  const short* Ag = A + (size_t)(tile_m + t8) * K + gsg * 8;
  const short* Bg = Bt + (size_t)(tile_n + qpart) * K + gsg * 8;
  short* Al0 = &As[0][tid * 8];
  short* Bl0 = &Bs[0][qpart * 64 + (tid & 7) * 8];

#define STG_A(P, ko)                                                           \
  do {                                                                         \
    GLD16(Ag + (ko), Al0 + (P) * 8192);                                        \
    GLD16(Ag + (size_t)64 * K + (ko), Al0 + (P) * 8192 + 4096);                \
  } while (0)
#define STG_B(P, h, ko)                                                        \
  do {                                                                         \
    GLD16(Bg + (size_t)((h) * 32) * K + (ko),                                  \
          Bl0 + (P) * 16384 + (h) * 2048);                                     \
    GLD16(Bg + (size_t)((h) * 32 + 128) * K + (ko),                            \
          Bl0 + (P) * 16384 + (h) * 2048 + 8192);                              \
  } while (0)

  const uint32_t asb = (uint32_t)(uintptr_t)&As[0][0];
  const uint32_t bsb = (uint32_t)(uintptr_t)&Bs[0][0];
  const uint32_t aab0 = asb + 2u * ((wm + l15) * 64 + (quad ^ l7) * 8);
  const uint32_t aab1 = asb + 2u * ((wm + l15) * 64 + (((4 + quad) ^ l7)) * 8);
  const uint32_t bab0 = bsb + 2u * ((wn + l15) * 64 + (quad ^ l7) * 8);
  const uint32_t bab1 = bsb + 2u * ((wn + l15) * 64 + (((4 + quad) ^ l7)) * 8);

#define RD_A(dst, P, mih)                                                      \
  do {                                                                         \
    DSR(dst[0][0], aab0, (P) * 16384 + (mih) * 4096);                          \
    DSR(dst[0][1], aab1, (P) * 16384 + (mih) * 4096);                          \
    DSR(dst[1][0], aab0, (P) * 16384 + (mih) * 4096 + 2048);                   \
    DSR(dst[1][1], aab1, (P) * 16384 + (mih) * 4096 + 2048);                   \
  } while (0)
#define RD_B(dst, P, njh)                                                      \
  do {                                                                         \
    DSR(dst[0][0], bab0, (P) * 32768 + (njh) * 4096);                          \
    DSR(dst[0][1], bab1, (P) * 32768 + (njh) * 4096);                          \
    DSR(dst[1][0], bab0, (P) * 32768 + (njh) * 4096 + 2048);                   \
    DSR(dst[1][1], bab1, (P) * 32768 + (njh) * 4096 + 2048);                   \
  } while (0)

  floatx4 acc[4][4];
#pragma unroll
  for (int i = 0; i < 4; ++i)
#pragma unroll
    for (int j = 0; j < 4; ++j) acc[i][j] = (floatx4){0.f, 0.f, 0.f, 0.f};

  short8x a[2][2], b0[2][2], b1[2][2];

#define MMQ(af, bf, mi0, nj0)                                                  \
  do {                                                                         \
    _Pragma("unroll") for (int i = 0; i < 2; ++i) {                            \
      _Pragma("unroll") for (int j = 0; j < 2; ++j) {                          \
        acc[(mi0) + i][(nj0) + j] = __builtin_amdgcn_mfma_f32_16x16x32_bf16(   \
            af[i][0], bf[j][0], acc[(mi0) + i][(nj0) + j], 0, 0, 0);           \
        acc[(mi0) + i][(nj0) + j] = __builtin_amdgcn_mfma_f32_16x16x32_bf16(   \
            af[i][1], bf[j][1], acc[(mi0) + i][(nj0) + j], 0, 0, 0);           \
      }                                                                        \
    }                                                                          \
  } while (0)

  constexpr int NK = K / BK;
  int ko;

  STG_B(0, 0, 0);
  STG_B(0, 1, 0);
  STG_A(0, 0);
  STG_B(1, 0, 64);
  STG_B(1, 1, 64);
  STG_A(1, 64);
  VMC(6);
  BAR();
  ko = 128;

#define TILE_STEADY(P)                                                         \
  do {                                                                         \
    RD_B(b0, P, 0);                                                            \
    RD_A(a, P, 0);                                                             \
    BAR();                                                                     \
    SP1();                                                                     \
    LGC(2);                                                                    \
    MM2(a, b0, 0, 0, 0, 0);                                                    \
    MM2(a, b0, 0, 1, 0, 0);                                                    \
    LGC(0);                                                                    \
    MM2(a, b0, 1, 0, 0, 0);                                                    \
    MM2(a, b0, 1, 1, 0, 0);                                                    \
    SP0();                                                                     \
    BAR();                                                                     \
    RD_B(b1, P, 1);                                                            \
    STG_B(P, 0, ko);                                                           \
    BAR();                                                                     \
    SP1();                                                                     \
    LGC(2);                                                                    \
    MM2(a, b1, 0, 0, 0, 2);                                                    \
    MM2(a, b1, 1, 0, 0, 2);                                                    \
    LGC(0);                                                                    \
    MM2(a, b1, 0, 1, 0, 2);                                                    \
    MM2(a, b1, 1, 1, 0, 2);                                                    \
    SP0();                                                                     \
    BAR();                                                                     \
    RD_A(a, P, 1);                                                             \
    STG_B(P, 1, ko);                                                           \
    BAR();                                                                     \
    SP1();                                                                     \
    LGC(2);                                                                    \
    MM2(a, b1, 0, 0, 2, 2);                                                    \
    MM2(a, b1, 0, 1, 2, 2);                                                    \
    LGC(0);                                                                    \
    MM2(a, b1, 1, 0, 2, 2);                                                    \
    MM2(a, b1, 1, 1, 2, 2);                                                    \
    SP0();                                                                     \
    BAR();                                                                     \
    STG_A(P, ko);                                                              \
    BAR();                                                                     \
    SP1();                                                                     \
    MMQ(a, b0, 2, 0);                                                          \
    SP0();                                                                     \
    VMC(6);                                                                    \
    BAR();                                                                     \
    ko += 64;                                                                  \
  } while (0)

#define TILE_TAIL1()                                                           \
  do {                                                                         \
    RD_B(b0, 0, 0);                                                            \
    RD_A(a, 0, 0);                                                             \
    BAR();                                                                     \
    LG0();                                                                     \
    SP1();                                                                     \
    MMQ(a, b0, 0, 0);                                                          \
    SP0();                                                                     \
    BAR();                                                                     \
    RD_B(b1, 0, 1);                                                            \
    BAR();                                                                     \
    LG0();                                                                     \
    SP1();                                                                     \
    MMQ(a, b1, 0, 2);                                                          \
    SP0();                                                                     \
    BAR();                                                                     \
    RD_A(a, 0, 1);                                                             \
    BAR();                                                                     \
    LG0();                                                                     \
    SP1();                                                                     \
    MMQ(a, b1, 2, 2);                                                          \
    SP0();                                                                     \
    BAR();                                                                     \
    SP1();                                                                     \
    MMQ(a, b0, 2, 0);                                                          \
    SP0();                                                                     \
    VMCM(0);                                                                   \
    BAR();                                                                     \
  } while (0)

#define TILE_TAIL2()                                                           \
  do {                                                                         \
    RD_B(b0, 1, 0);                                                            \
    RD_A(a, 1, 0);                                                             \
    RD_B(b1, 1, 1);                                                            \
    LG0();                                                                     \
    SP1();                                                                     \
    MMQ(a, b0, 0, 0);                                                          \
    MMQ(a, b1, 0, 2);                                                          \
    SP0();                                                                     \
    RD_A(a, 1, 1);                                                             \
    LG0();                                                                     \
    SP1();                                                                     \
    MMQ(a, b1, 2, 2);                                                          \
    MMQ(a, b0, 2, 0);                                                          \
    SP0();                                                                     \
  } while (0)

  for (int it = 0; it < (NK - 2) / 2; ++it) {
    TILE_STEADY(0);
    TILE_STEADY(1);
  }
  TILE_TAIL1();
  TILE_TAIL2();

#pragma unroll
  for (int n = 0; n < 4; ++n) {
    const int col = tile_n + wn + n * 16 + l15;
    const float bv = bias[col];
#pragma unroll
    for (int m = 0; m < 4; ++m) {
      const int row0 = tile_m + wm + m * 16 + quad * 4;
#pragma unroll
      for (int r = 0; r < 4; ++r) {
        const size_t idx = (size_t)(row0 + r) * N + col;
        float v = acc[m][n][r] + bv;
        if (MODE == 0) {
          v = v > 0.f ? v : 0.f;
          Cb[idx] = f2bf(v);
        } else if (MODE == 1) {
          accbuf[idx] = v;
          ytbf[idx] = f2bf(y[idx] + 0.5f * v);
        } else if (MODE == 2) {
          float a2 = accbuf[idx];
          accbuf[idx] = a2 + 4.f * v;
          ytbf[idx] = f2bf(y[idx] - a2 + 2.f * v);
        } else {
          yout[idx] = y[idx] + (1.f / 6.f) * (accbuf[idx] + v);
        }
      }
    }
  }
}

// W[K][N] fp32 -> Wt[N][K] bf16 (B^T layout)
__global__ __launch_bounds__(256) void transpose_bf16(
    const float* __restrict__ W, short* __restrict__ Wt, int K, int N) {
  __shared__ float t[32][33];
  int tx = threadIdx.x & 31, ty = threadIdx.x >> 5;
  int k0 = blockIdx.y * 32, n0 = blockIdx.x * 32;
#pragma unroll
  for (int r = 0; r < 32; r += 8)
    t[ty + r][tx] = W[(size_t)(k0 + ty + r) * N + (n0 + tx)];
  __syncthreads();
#pragma unroll
  for (int r = 0; r < 32; r += 8)
    Wt[(size_t)(n0 + ty + r) * K + (k0 + tx)] = f2bf(t[tx][ty + r]);
}

__global__ __launch_bounds__(256) void init_y_kernel(
    const float* __restrict__ x, float* __restrict__ y,
    short* __restrict__ ybf, int n4) {
  int i = blockIdx.x * 256 + threadIdx.x;
  if (i >= n4) return;
  float4 v = ((const float4*)x)[i];
  ((float4*)y)[i] = v;
  short4 b;
  b.x = f2bf(v.x);
  b.y = f2bf(v.y);
  b.z = f2bf(v.z);
  b.w = f2bf(v.w);
  ((short4*)ybf)[i] = b;
}

extern "C" void kernel_launch(void* const* d_in, const int* in_sizes, int n_in,
                              void* d_out, int out_size, void* d_ws,
                              size_t ws_size, hipStream_t stream) {
  const float* x = (const float*)d_in[0];
  const float* W1 = (const float*)d_in[1];
  const float* b1 = (const float*)d_in[2];
  const float* W2 = (const float*)d_in[3];
  const float* b2 = (const float*)d_in[4];
  const float* W3 = (const float*)d_in[5];
  const float* b3 = (const float*)d_in[6];

  const int B = 8192, D = 1024, H = 2048;
  char* ws = (char*)d_ws;
  short* W1t = (short*)(ws + (0ull << 20));   // [H,D] bf16   4 MB
  short* W2t = (short*)(ws + (4ull << 20));   // [H,H] bf16   8 MB
  short* W3t = (short*)(ws + (12ull << 20));  // [D,H] bf16   4 MB
  short* ybf = (short*)(ws + (16ull << 20));  // [B,D] bf16  16 MB
  short* h1 = (short*)(ws + (32ull << 20));   // [B,H] bf16  32 MB
  short* h2 = (short*)(ws + (64ull << 20));   // [B,H] bf16  32 MB
  float* acc = (float*)(ws + (96ull << 20));  // [B,D] f32   32 MB
  float* y = (float*)(ws + (128ull << 20));   // [B,D] f32   32 MB
  float* out = (float*)d_out;

  transpose_bf16<<<dim3(H / 32, D / 32), 256, 0, stream>>>(W1, W1t, D, H);
  transpose_bf16<<<dim3(H / 32, H / 32), 256, 0, stream>>>(W2, W2t, H, H);
  transpose_bf16<<<dim3(D / 32, H / 32), 256, 0, stream>>>(W3, W3t, H, D);
  init_y_kernel<<<(B * D / 4 + 255) / 256, 256, 0, stream>>>(x, y, ybf,
                                                             B * D / 4);

  const dim3 g12(H / 256, B / 256);  // (8, 32) = 256 blocks, 1/CU
  const dim3 g3(D / BN, B / BM);     // (4, 64) = 256 blocks

  // Kutta RK3, single step h=1: stages mode 1, 2, 3.
  for (int stg = 1; stg <= 3; ++stg) {
    gemm256<1024><<<g12, 512, 0, stream>>>(ybf, W1t, b1, h1, H);
    gemm256<2048><<<g12, 512, 0, stream>>>(h1, W2t, b2, h2, H);
    if (stg == 1)
      gemm8p<2048, 1><<<g3, 512, 0, stream>>>(h2, W3t, b3, nullptr, acc, y,
                                              nullptr, ybf, D);
    else if (stg == 2)
      gemm8p<2048, 2><<<g3, 512, 0, stream>>>(h2, W3t, b3, nullptr, acc, y,
                                              nullptr, ybf, D);
    else
      gemm8p<2048, 3><<<g3, 512, 0, stream>>>(h2, W3t, b3, nullptr, acc, y,
                                              out, ybf, D);
  }
}